// Round 23
// baseline (77.836 us; speedup 1.0000x reference)
//
#include <hip/hip_runtime.h>
#include <hip/hip_bf16.h>
#include <stdint.h>

// Problem constants (fixed by setup_inputs)
// B=8, S=1024, HID=768, NH=12, D=64, total=6528
// LENGTHS = {1024,896,768,640,1024,512,768,896}  (all multiples of 128)
//
// R23 = r22 (77.09us) + ONE delta: attn __launch_bounds__(256, 3).
// r12/r13 re-audit: the r12 regression was ENTIRELY __builtin_exp2f's
// no-fast-math lowering (r13 isolated it at +11us); lb(256,3)+perm in the
// same bundle was neutral-to-positive. The r22 attn is leaner (~130-150
// VGPR live, K=32 PV, no P-LDS), fitting the 168-VGPR cap for 3 waves/SIMD;
// LDS 32KB x 3 = 96 < 160KB. 3 blocks/CU = +50% TLP over the per-tile
// barrier vmcnt-drains (the established attn bottleneck; r20 showed a
// residency slot on this kernel is worth ~5us). All else byte-identical.

typedef __attribute__((ext_vector_type(8))) __bf16 bf16x8;
typedef __attribute__((ext_vector_type(8))) short short8;
typedef __attribute__((ext_vector_type(4))) short short4v;
typedef __attribute__((ext_vector_type(4))) float f32x4;
typedef __attribute__((ext_vector_type(4))) unsigned int u32x4;
typedef unsigned int u32;

#define AS1 __attribute__((address_space(1)))
#define AS3 __attribute__((address_space(3)))

static __device__ __forceinline__ unsigned short f2bf(float x) {
  unsigned u = __builtin_bit_cast(unsigned, x);
  u += 0x7fffu + ((u >> 16) & 1u);   // RTNE
  return (unsigned short)(u >> 16);
}
static __device__ __forceinline__ bf16x8 ld8s(const short* p) {
  return __builtin_bit_cast(bf16x8, *(const short8*)p);
}
static __device__ __forceinline__ u32 cvtpk(float lo, float hi) {
  u32 r;
  asm("v_cvt_pk_bf16_f32 %0, %1, %2" : "=v"(r) : "v"(lo), "v"(hi));
  return r;
}
// single-instruction 2^x (flush-to-zero below -126: fine for masked keys)
static __device__ __forceinline__ float vexp2(float x) {
  float r;
  asm("v_exp_f32 %0, %1" : "=v"(r) : "v"(x));
  return r;
}

__device__ const float g_slope[12] = {
  0.6299605249f, 0.3968502630f, 0.25f,          0.1574901312f,
  0.0992125657f, 0.0625f,       0.0393725328f,  0.0248031414f,
  0.015625f,     0.0098431332f, 0.0062007854f,  0.00390625f
};

// ---------------------------------------------------------------------------
// Kernel 0: f32 -> bf16 streaming convert of hidden & Wqkv (r22 exact).
// ---------------------------------------------------------------------------
__global__ __launch_bounds__(256) void convert_in(
    const float* __restrict__ hidden, const float* __restrict__ W,
    short* __restrict__ hb, short* __restrict__ wb)
{
  constexpr int NA = 6528 * 768;
  constexpr int NW = 2304 * 768;
  const int tot4 = (NA + NW) / 4;
  for (int idx = blockIdx.x * 256 + threadIdx.x; idx < tot4; idx += gridDim.x * 256) {
    const int e0 = idx * 4;
    const float* src; short* dst; int off;
    if (e0 < NA) { src = hidden; dst = hb; off = e0; }
    else         { src = W;      dst = wb; off = e0 - NA; }
    f32x4 v = *((const f32x4*)(src + off));
    short4v o;
    o[0] = (short)f2bf(v[0]); o[1] = (short)f2bf(v[1]);
    o[2] = (short)f2bf(v[2]); o[3] = (short)f2bf(v[3]);
    *(short4v*)(dst + off) = o;
  }
}

// ---------------------------------------------------------------------------
// Kernel 1: qkv GEMM (r22 exact). BM=256 BN=128 BK=64, 12 K-steps, 8-chunk
// XOR swizzle, 2-phase __syncthreads dbuf. q pre-scaled 0.125*log2e.
// ---------------------------------------------------------------------------
__global__ __launch_bounds__(256, 2) void qkv_gemm(
    const short* __restrict__ A, const short* __restrict__ W,
    const float* __restrict__ bias,
    short* __restrict__ qws, short* __restrict__ kws, short* __restrict__ vtws)
{
  constexpr int CUb[9] = {0,1024,1920,2688,3328,4352,4864,5632,6528};
  __shared__ __align__(16) short As[256 * 64];   // 32 KB
  __shared__ __align__(16) short Bs[128 * 64];   // 16 KB
  const int tid  = threadIdx.x;
  const int lane = tid & 63, w = tid >> 6;
  const int g = lane >> 4, c = lane & 15;
  const int wm = w >> 1, wn = w & 1;
  const int bm = blockIdx.x, bn = blockIdx.y;

  const short* Ab = A + (size_t)bm * 256 * 768;
  const short* Wb = W + (size_t)bn * 128 * 768;

  f32x4 acc[8][4] = {};
  const int sR8 = lane >> 3;
  const int sC8 = (lane & 7) ^ sR8;

  for (int kt = 0; kt < 12; ++kt) {
    if (kt) __syncthreads();
#pragma unroll
    for (int i = 0; i < 8; ++i) {        // A: 32 insts (8/wave)
      const int j = w * 8 + i;
      const AS1 unsigned int* ga =
        (const AS1 unsigned int*)(Ab + (size_t)(j * 8 + sR8) * 768 + kt * 64 + sC8 * 8);
      __builtin_amdgcn_global_load_lds(ga, (AS3 unsigned int*)&As[j * 512], 16, 0, 0);
    }
#pragma unroll
    for (int i = 0; i < 4; ++i) {        // B: 16 insts (4/wave)
      const int j = w * 4 + i;
      const AS1 unsigned int* gb =
        (const AS1 unsigned int*)(Wb + (size_t)(j * 8 + sR8) * 768 + kt * 64 + sC8 * 8);
      __builtin_amdgcn_global_load_lds(gb, (AS3 unsigned int*)&Bs[j * 512], 16, 0, 0);
    }
    __syncthreads();

#pragma unroll
    for (int kh = 0; kh < 2; ++kh) {
      const int xg = (((kh * 4 + g) ^ (c & 7)) << 3);
      bf16x8 bfr[4];
#pragma unroll
      for (int nt = 0; nt < 4; ++nt)
        bfr[nt] = ld8s(&Bs[(wn * 64 + nt * 16 + c) * 64 + xg]);
#pragma unroll
      for (int mt = 0; mt < 8; ++mt) {
        bf16x8 af = ld8s(&As[(wm * 128 + mt * 16 + c) * 64 + xg]);
#pragma unroll
        for (int nt = 0; nt < 4; ++nt)
          acc[mt][nt] = __builtin_amdgcn_mfma_f32_16x16x32_bf16(af, bfr[nt], acc[mt][nt], 0, 0, 0);
      }
    }
  }

  const int row0 = bm * 256 + wm * 128;
  if (row0 >= 6528) return;
  int b = 0;
#pragma unroll
  for (int i = 0; i < 8; ++i) if (row0 >= CUb[i + 1]) b = i + 1;
  const int col0  = bn * 128 + wn * 64;
  const int which = col0 / 768;
  const int hh    = (col0 % 768) / 64;
  const int srow0 = row0 - CUb[b];

  float bb[4];
#pragma unroll
  for (int nt = 0; nt < 4; ++nt) bb[nt] = bias[col0 + nt * 16 + c];

  if (which < 2) {
    // q pre-scaled by (1/8)*log2(e) so attn's softmax is a bare fma+v_exp
    const float sc = which ? 1.0f : 0.18033688011112042f;
    short* dst = (which ? kws : qws) + (size_t)(b * 12 + hh) * 1024 * 64;
#pragma unroll
    for (int mt = 0; mt < 8; ++mt)
#pragma unroll
      for (int nt = 0; nt < 4; ++nt)
#pragma unroll
        for (int r = 0; r < 4; ++r) {
          const int s = srow0 + mt * 16 + g * 4 + r;
          dst[(size_t)s * 64 + nt * 16 + c] = (short)f2bf((acc[mt][nt][r] + bb[nt]) * sc);
        }
  } else {
    short* dst = vtws + (size_t)(b * 12 + hh) * 64 * 1024;
#pragma unroll
    for (int mt = 0; mt < 8; ++mt)
#pragma unroll
      for (int nt = 0; nt < 4; ++nt) {
        const int s = srow0 + mt * 16 + g * 4;
        short4v pk;
        pk[0] = (short)f2bf(acc[mt][nt][0] + bb[nt]);
        pk[1] = (short)f2bf(acc[mt][nt][1] + bb[nt]);
        pk[2] = (short)f2bf(acc[mt][nt][2] + bb[nt]);
        pk[3] = (short)f2bf(acc[mt][nt][3] + bb[nt]);
        *(short4v*)&dst[(size_t)(nt * 16 + c) * 1024 + s] = pk;
      }
  }
}

// ---------------------------------------------------------------------------
// Kernel 2: flash attention (r22 structure) — swapped-QK^T with bit-permuted
// K rows, in-register P, K=32 PV, KVBLK=64 dbuf. ONLY delta: lb(256,3).
// ---------------------------------------------------------------------------
__global__ __launch_bounds__(256, 3) void attn(
    const short* __restrict__ qws, const short* __restrict__ kws,
    const short* __restrict__ vtws, float* __restrict__ out)
{
  constexpr int CU[9]  = {0,1024,1920,2688,3328,4352,4864,5632,6528};
  constexpr int CQT[9] = {0,8,15,21,26,34,38,44,51};
  __shared__ __align__(16) short Ks[2][64 * 64];
  __shared__ __align__(16) short Vs[2][64 * 64];
  const int tid = threadIdx.x, lane = tid & 63, w = tid >> 6;
  const int g = lane >> 4, c = lane & 15;
  const int h = blockIdx.y;
  const int gq = blockIdx.x;
  int b = 0;
#pragma unroll
  for (int i = 0; i < 8; ++i) if (gq >= CQT[i + 1]) b = i + 1;
  const int qt = gq - CQT[b];
  const int Lb = CU[b + 1] - CU[b];
  const int sb = qt * 128 + w * 32;
  const size_t bh = (size_t)(b * 12 + h) * 1024 * 64;
  const short* qp = qws + bh;
  const short* kp = kws + bh;
  const short* vp = vtws + bh;
  const float slope2 = g_slope[h] * 1.4426950408889634f;   // slope * log2(e)

  const int sRow = lane >> 3;
  const int sChk = (lane & 7) ^ (sRow & 7);

  bf16x8 qf[2][2];
#pragma unroll
  for (int qh = 0; qh < 2; ++qh)
#pragma unroll
    for (int ks = 0; ks < 2; ++ks)
      qf[qh][ks] = ld8s(qp + (size_t)(sb + qh * 16 + c) * 64 + ks * 32 + g * 8);

  float srowf[2];
#pragma unroll
  for (int qh = 0; qh < 2; ++qh) srowf[qh] = (float)(sb + qh * 16 + c);

  f32x4 accO[2][4] = {};
  float l_part[2] = {};

  auto kaddr = [&](int row, int chunk) { return row * 64 + ((chunk ^ (row & 7)) << 3); };
  // K row bit-permutation (see r22): LDS row p holds K[t0 + fperm(p)] so QK's
  // C-layout gives k = 32*(nt>>1) + 8g + 4*(nt&1) + r (16x16x32 A-frag).
  auto fperm = [&](int p) {
    return (p & 32) | (((p >> 2) & 3) << 3) | (((p >> 4) & 1) << 2) | (p & 3);
  };

  auto stageKV = [&](int t, int buf) {
#pragma unroll
    for (int i = 0; i < 2; ++i) {
      const int j = w * 2 + i;
      const int dRow = j * 8 + sRow;
      const AS1 unsigned int* gk =
        (const AS1 unsigned int*)(kp + (size_t)(t + fperm(dRow)) * 64 + sChk * 8);
      __builtin_amdgcn_global_load_lds(gk, (AS3 unsigned int*)&Ks[buf][j * 512], 16, 0, 0);
      const AS1 unsigned int* gv =
        (const AS1 unsigned int*)(vp + (size_t)dRow * 1024 + t + sChk * 8);
      __builtin_amdgcn_global_load_lds(gv, (AS3 unsigned int*)&Vs[buf][j * 512], 16, 0, 0);
    }
  };

  // ---- prologue: stage tile 0 into buf 0 ----
  stageKV(0, 0);
  __syncthreads();

  int cur = 0;
  for (int t0 = 0; t0 < Lb; t0 += 64) {
    if (t0 + 64 < Lb) stageKV(t0 + 64, cur ^ 1);

    // ---- S^T = K Q ----
    f32x4 sa[2][4];
    __builtin_amdgcn_s_setprio(1);
#pragma unroll
    for (int nt = 0; nt < 4; ++nt) {
      bf16x8 kf0 = ld8s(&Ks[cur][kaddr(nt * 16 + c, g)]);
      bf16x8 kf1 = ld8s(&Ks[cur][kaddr(nt * 16 + c, 4 + g)]);
#pragma unroll
      for (int qh = 0; qh < 2; ++qh) {
        f32x4 z = {};
        z = __builtin_amdgcn_mfma_f32_16x16x32_bf16(kf0, qf[qh][0], z, 0, 0, 0);
        sa[qh][nt] = __builtin_amdgcn_mfma_f32_16x16x32_bf16(kf1, qf[qh][1], z, 0, 0, 0);
      }
    }
    __builtin_amdgcn_s_setprio(0);

    // ---- softmax: k = t0 + 32*(nt>>1) + 8g + 4*(nt&1) + r; pack K=32 frags -
    u32x4 pa32[2][2];
#pragma unroll
    for (int qh = 0; qh < 2; ++qh) {
#pragma unroll
      for (int nt = 0; nt < 4; ++nt) {
        const float tg = (float)(t0 + 32 * (nt >> 1) + 4 * (nt & 1) + 8 * g);
        float p[4];
#pragma unroll
        for (int r = 0; r < 4; ++r) {
          const float d = srowf[qh] - (tg + (float)r);
          p[r] = vexp2(fmaf(-slope2, fabsf(d), sa[qh][nt][r]));
          l_part[qh] += p[r];
        }
        pa32[qh][nt >> 1][(nt & 1) * 2 + 0] = cvtpk(p[0], p[1]);
        pa32[qh][nt >> 1][(nt & 1) * 2 + 1] = cvtpk(p[2], p[3]);
      }
    }

    // ---- O += P V : 16 x v_mfma_16x16x32, V via b128 ----
    __builtin_amdgcn_s_setprio(1);
#pragma unroll
    for (int ntd = 0; ntd < 4; ++ntd) {
#pragma unroll
      for (int s = 0; s < 2; ++s) {
        bf16x8 vb = ld8s(&Vs[cur][kaddr(c + 16 * ntd, 4 * s + g)]);
        accO[0][ntd] = __builtin_amdgcn_mfma_f32_16x16x32_bf16(
            __builtin_bit_cast(bf16x8, pa32[0][s]), vb, accO[0][ntd], 0, 0, 0);
        accO[1][ntd] = __builtin_amdgcn_mfma_f32_16x16x32_bf16(
            __builtin_bit_cast(bf16x8, pa32[1][s]), vb, accO[1][ntd], 0, 0, 0);
      }
    }
    __builtin_amdgcn_s_setprio(0);

    __syncthreads();
    cur ^= 1;
  }

  // ---- row-sum reduce + redistribute + store ----
  float linv[2][4];
#pragma unroll
  for (int qh = 0; qh < 2; ++qh) {
    float rs = l_part[qh];
    rs += __shfl_xor(rs, 16, 64);
    rs += __shfl_xor(rs, 32, 64);
    const float inv = 1.0f / rs;
#pragma unroll
    for (int r = 0; r < 4; ++r)
      linv[qh][r] = __shfl(inv, g * 4 + r, 64);
  }

#pragma unroll
  for (int qh = 0; qh < 2; ++qh)
#pragma unroll
    for (int r = 0; r < 4; ++r) {
      const int srow = sb + qh * 16 + g * 4 + r;
      const size_t ob = (size_t)(CU[b] + srow) * 768 + h * 64;
#pragma unroll
      for (int ntd = 0; ntd < 4; ++ntd)
        out[ob + ntd * 16 + c] = accO[qh][ntd][r] * linv[qh][r];
    }
}

extern "C" void kernel_launch(void* const* d_in, const int* in_sizes, int n_in,
                              void* d_out, int out_size, void* d_ws, size_t ws_size,
                              hipStream_t stream) {
  const float* hidden = (const float*)d_in[0];
  const float* Wqkv_w = (const float*)d_in[1];
  const float* Wqkv_b = (const float*)d_in[2];

  constexpr size_t NA_PAD = (size_t)6656 * 768;
  constexpr size_t NW = (size_t)2304 * 768;
  constexpr size_t NP = (size_t)8 * 12 * 1024 * 64;

  short* hb   = (short*)d_ws;
  short* wb   = hb + NA_PAD;
  short* qws  = wb + NW;
  short* kws  = qws + NP;
  short* vtws = kws + NP;

  convert_in<<<dim3(2048), 256, 0, stream>>>(hidden, Wqkv_w, hb, wb);
  qkv_gemm<<<dim3(26, 18), 256, 0, stream>>>(hb, wb, Wqkv_b, qws, kws, vtws);
  attn<<<dim3(51, 12), 256, 0, stream>>>(qws, kws, vtws, (float*)d_out);
}

// Round 24
// 77.383 us; speedup vs baseline: 1.0059x; 1.0059x over previous
//
#include <hip/hip_runtime.h>
#include <hip/hip_bf16.h>
#include <stdint.h>

// Problem constants (fixed by setup_inputs)
// B=8, S=1024, HID=768, NH=12, D=64, total=6528
// LENGTHS = {1024,896,768,640,1024,512,768,896}  (all multiples of 128)
//
// FINAL = r22 EXACT (best: 77.09us). r23's attn lb(256,3) was neutral-to-
// negative (77.84) -> reverted per pre-commitment.
//   convert: streaming f32->bf16 (~8us, HBM-bound)
//   gemm: BM=256 BN=128 BK=64 (12 K-steps), gload_lds w16, 8-chunk XOR
//         swizzle, 2-phase __syncthreads dbuf, q pre-scaled 0.125*log2e (~27us)
//   attn: KVBLK=64 dbuf; swapped-QK^T with bit-permuted K rows so the QK
//         C-layout IS the 16x16x32 A-frag layout -> in-register P
//         (v_cvt_pk_bf16_f32) feeds K=32 PV MFMA (16 mfma + 8 b128/tile);
//         fixed-max base-2 softmax, 1-inst v_exp_f32; deferred row-sum (~35us)

typedef __attribute__((ext_vector_type(8))) __bf16 bf16x8;
typedef __attribute__((ext_vector_type(8))) short short8;
typedef __attribute__((ext_vector_type(4))) short short4v;
typedef __attribute__((ext_vector_type(4))) float f32x4;
typedef __attribute__((ext_vector_type(4))) unsigned int u32x4;
typedef unsigned int u32;

#define AS1 __attribute__((address_space(1)))
#define AS3 __attribute__((address_space(3)))

static __device__ __forceinline__ unsigned short f2bf(float x) {
  unsigned u = __builtin_bit_cast(unsigned, x);
  u += 0x7fffu + ((u >> 16) & 1u);   // RTNE
  return (unsigned short)(u >> 16);
}
static __device__ __forceinline__ bf16x8 ld8s(const short* p) {
  return __builtin_bit_cast(bf16x8, *(const short8*)p);
}
static __device__ __forceinline__ u32 cvtpk(float lo, float hi) {
  u32 r;
  asm("v_cvt_pk_bf16_f32 %0, %1, %2" : "=v"(r) : "v"(lo), "v"(hi));
  return r;
}
// single-instruction 2^x (flush-to-zero below -126: fine for masked keys)
static __device__ __forceinline__ float vexp2(float x) {
  float r;
  asm("v_exp_f32 %0, %1" : "=v"(r) : "v"(x));
  return r;
}

__device__ const float g_slope[12] = {
  0.6299605249f, 0.3968502630f, 0.25f,          0.1574901312f,
  0.0992125657f, 0.0625f,       0.0393725328f,  0.0248031414f,
  0.015625f,     0.0098431332f, 0.0062007854f,  0.00390625f
};

// ---------------------------------------------------------------------------
// Kernel 0: f32 -> bf16 streaming convert of hidden & Wqkv.
// ---------------------------------------------------------------------------
__global__ __launch_bounds__(256) void convert_in(
    const float* __restrict__ hidden, const float* __restrict__ W,
    short* __restrict__ hb, short* __restrict__ wb)
{
  constexpr int NA = 6528 * 768;
  constexpr int NW = 2304 * 768;
  const int tot4 = (NA + NW) / 4;
  for (int idx = blockIdx.x * 256 + threadIdx.x; idx < tot4; idx += gridDim.x * 256) {
    const int e0 = idx * 4;
    const float* src; short* dst; int off;
    if (e0 < NA) { src = hidden; dst = hb; off = e0; }
    else         { src = W;      dst = wb; off = e0 - NA; }
    f32x4 v = *((const f32x4*)(src + off));
    short4v o;
    o[0] = (short)f2bf(v[0]); o[1] = (short)f2bf(v[1]);
    o[2] = (short)f2bf(v[2]); o[3] = (short)f2bf(v[3]);
    *(short4v*)(dst + off) = o;
  }
}

// ---------------------------------------------------------------------------
// Kernel 1: qkv GEMM. BM=256 BN=128 BK=64; 4 waves (2M x 2N), wave tile
// 128x64, acc[8][4]. 8-chunk-XOR swizzled LDS (pre-swizzled gload_lds source
// + XOR'd ds_read_b128), 2-phase __syncthreads dbuf, 12 K-steps.
// q PRE-SCALED by 0.125*log2e. Pad rows >= 6528: stores skipped.
// ---------------------------------------------------------------------------
__global__ __launch_bounds__(256, 2) void qkv_gemm(
    const short* __restrict__ A, const short* __restrict__ W,
    const float* __restrict__ bias,
    short* __restrict__ qws, short* __restrict__ kws, short* __restrict__ vtws)
{
  constexpr int CUb[9] = {0,1024,1920,2688,3328,4352,4864,5632,6528};
  __shared__ __align__(16) short As[256 * 64];   // 32 KB
  __shared__ __align__(16) short Bs[128 * 64];   // 16 KB
  const int tid  = threadIdx.x;
  const int lane = tid & 63, w = tid >> 6;
  const int g = lane >> 4, c = lane & 15;
  const int wm = w >> 1, wn = w & 1;
  const int bm = blockIdx.x, bn = blockIdx.y;

  const short* Ab = A + (size_t)bm * 256 * 768;
  const short* Wb = W + (size_t)bn * 128 * 768;

  f32x4 acc[8][4] = {};
  const int sR8 = lane >> 3;
  const int sC8 = (lane & 7) ^ sR8;

  for (int kt = 0; kt < 12; ++kt) {
    if (kt) __syncthreads();
#pragma unroll
    for (int i = 0; i < 8; ++i) {        // A: 32 insts (8/wave)
      const int j = w * 8 + i;
      const AS1 unsigned int* ga =
        (const AS1 unsigned int*)(Ab + (size_t)(j * 8 + sR8) * 768 + kt * 64 + sC8 * 8);
      __builtin_amdgcn_global_load_lds(ga, (AS3 unsigned int*)&As[j * 512], 16, 0, 0);
    }
#pragma unroll
    for (int i = 0; i < 4; ++i) {        // B: 16 insts (4/wave)
      const int j = w * 4 + i;
      const AS1 unsigned int* gb =
        (const AS1 unsigned int*)(Wb + (size_t)(j * 8 + sR8) * 768 + kt * 64 + sC8 * 8);
      __builtin_amdgcn_global_load_lds(gb, (AS3 unsigned int*)&Bs[j * 512], 16, 0, 0);
    }
    __syncthreads();

#pragma unroll
    for (int kh = 0; kh < 2; ++kh) {
      const int xg = (((kh * 4 + g) ^ (c & 7)) << 3);
      bf16x8 bfr[4];
#pragma unroll
      for (int nt = 0; nt < 4; ++nt)
        bfr[nt] = ld8s(&Bs[(wn * 64 + nt * 16 + c) * 64 + xg]);
#pragma unroll
      for (int mt = 0; mt < 8; ++mt) {
        bf16x8 af = ld8s(&As[(wm * 128 + mt * 16 + c) * 64 + xg]);
#pragma unroll
        for (int nt = 0; nt < 4; ++nt)
          acc[mt][nt] = __builtin_amdgcn_mfma_f32_16x16x32_bf16(af, bfr[nt], acc[mt][nt], 0, 0, 0);
      }
    }
  }

  const int row0 = bm * 256 + wm * 128;
  if (row0 >= 6528) return;
  int b = 0;
#pragma unroll
  for (int i = 0; i < 8; ++i) if (row0 >= CUb[i + 1]) b = i + 1;
  const int col0  = bn * 128 + wn * 64;
  const int which = col0 / 768;
  const int hh    = (col0 % 768) / 64;
  const int srow0 = row0 - CUb[b];

  float bb[4];
#pragma unroll
  for (int nt = 0; nt < 4; ++nt) bb[nt] = bias[col0 + nt * 16 + c];

  if (which < 2) {
    // q pre-scaled by (1/8)*log2(e) so attn's softmax is a bare fma+v_exp
    const float sc = which ? 1.0f : 0.18033688011112042f;
    short* dst = (which ? kws : qws) + (size_t)(b * 12 + hh) * 1024 * 64;
#pragma unroll
    for (int mt = 0; mt < 8; ++mt)
#pragma unroll
      for (int nt = 0; nt < 4; ++nt)
#pragma unroll
        for (int r = 0; r < 4; ++r) {
          const int s = srow0 + mt * 16 + g * 4 + r;
          dst[(size_t)s * 64 + nt * 16 + c] = (short)f2bf((acc[mt][nt][r] + bb[nt]) * sc);
        }
  } else {
    short* dst = vtws + (size_t)(b * 12 + hh) * 64 * 1024;
#pragma unroll
    for (int mt = 0; mt < 8; ++mt)
#pragma unroll
      for (int nt = 0; nt < 4; ++nt) {
        const int s = srow0 + mt * 16 + g * 4;
        short4v pk;
        pk[0] = (short)f2bf(acc[mt][nt][0] + bb[nt]);
        pk[1] = (short)f2bf(acc[mt][nt][1] + bb[nt]);
        pk[2] = (short)f2bf(acc[mt][nt][2] + bb[nt]);
        pk[3] = (short)f2bf(acc[mt][nt][3] + bb[nt]);
        *(short4v*)&dst[(size_t)(nt * 16 + c) * 1024 + s] = pk;
      }
  }
}

// ---------------------------------------------------------------------------
// Kernel 2: flash attention — swapped-QK^T, in-register P, KVBLK=64 dbuf.
// K staged with bit-permuted source rows so PV runs as K=32 MFMA.
// ---------------------------------------------------------------------------
__global__ __launch_bounds__(256, 2) void attn(
    const short* __restrict__ qws, const short* __restrict__ kws,
    const short* __restrict__ vtws, float* __restrict__ out)
{
  constexpr int CU[9]  = {0,1024,1920,2688,3328,4352,4864,5632,6528};
  constexpr int CQT[9] = {0,8,15,21,26,34,38,44,51};
  __shared__ __align__(16) short Ks[2][64 * 64];
  __shared__ __align__(16) short Vs[2][64 * 64];
  const int tid = threadIdx.x, lane = tid & 63, w = tid >> 6;
  const int g = lane >> 4, c = lane & 15;
  const int h = blockIdx.y;
  const int gq = blockIdx.x;
  int b = 0;
#pragma unroll
  for (int i = 0; i < 8; ++i) if (gq >= CQT[i + 1]) b = i + 1;
  const int qt = gq - CQT[b];
  const int Lb = CU[b + 1] - CU[b];
  const int sb = qt * 128 + w * 32;
  const size_t bh = (size_t)(b * 12 + h) * 1024 * 64;
  const short* qp = qws + bh;
  const short* kp = kws + bh;
  const short* vp = vtws + bh;
  const float slope2 = g_slope[h] * 1.4426950408889634f;   // slope * log2(e)

  const int sRow = lane >> 3;
  const int sChk = (lane & 7) ^ (sRow & 7);

  bf16x8 qf[2][2];
#pragma unroll
  for (int qh = 0; qh < 2; ++qh)
#pragma unroll
    for (int ks = 0; ks < 2; ++ks)
      qf[qh][ks] = ld8s(qp + (size_t)(sb + qh * 16 + c) * 64 + ks * 32 + g * 8);

  float srowf[2];
#pragma unroll
  for (int qh = 0; qh < 2; ++qh) srowf[qh] = (float)(sb + qh * 16 + c);

  f32x4 accO[2][4] = {};
  float l_part[2] = {};

  auto kaddr = [&](int row, int chunk) { return row * 64 + ((chunk ^ (row & 7)) << 3); };
  // K row bit-permutation: LDS row p holds K[t0 + fperm(p)] so that QK's
  // C-layout labels lane (g,c) sa[r] with k = 32*(nt>>1) + 8g + 4*(nt&1) + r
  // (= the 16x16x32 A-frag layout for PV). Bijection: output bits
  // [b5][b3][b2][b4][b1][b0].
  auto fperm = [&](int p) {
    return (p & 32) | (((p >> 2) & 3) << 3) | (((p >> 4) & 1) << 2) | (p & 3);
  };

  auto stageKV = [&](int t, int buf) {
#pragma unroll
    for (int i = 0; i < 2; ++i) {
      const int j = w * 2 + i;
      const int dRow = j * 8 + sRow;
      const AS1 unsigned int* gk =
        (const AS1 unsigned int*)(kp + (size_t)(t + fperm(dRow)) * 64 + sChk * 8);
      __builtin_amdgcn_global_load_lds(gk, (AS3 unsigned int*)&Ks[buf][j * 512], 16, 0, 0);
      const AS1 unsigned int* gv =
        (const AS1 unsigned int*)(vp + (size_t)dRow * 1024 + t + sChk * 8);
      __builtin_amdgcn_global_load_lds(gv, (AS3 unsigned int*)&Vs[buf][j * 512], 16, 0, 0);
    }
  };

  // ---- prologue: stage tile 0 into buf 0 ----
  stageKV(0, 0);
  __syncthreads();

  int cur = 0;
  for (int t0 = 0; t0 < Lb; t0 += 64) {
    if (t0 + 64 < Lb) stageKV(t0 + 64, cur ^ 1);

    // ---- S^T = K Q (rows relabeled by fperm) ----
    f32x4 sa[2][4];
    __builtin_amdgcn_s_setprio(1);
#pragma unroll
    for (int nt = 0; nt < 4; ++nt) {
      bf16x8 kf0 = ld8s(&Ks[cur][kaddr(nt * 16 + c, g)]);
      bf16x8 kf1 = ld8s(&Ks[cur][kaddr(nt * 16 + c, 4 + g)]);
#pragma unroll
      for (int qh = 0; qh < 2; ++qh) {
        f32x4 z = {};
        z = __builtin_amdgcn_mfma_f32_16x16x32_bf16(kf0, qf[qh][0], z, 0, 0, 0);
        sa[qh][nt] = __builtin_amdgcn_mfma_f32_16x16x32_bf16(kf1, qf[qh][1], z, 0, 0, 0);
      }
    }
    __builtin_amdgcn_s_setprio(0);

    // ---- softmax: sa[qh][nt][r] is k = t0 + 32*(nt>>1) + 8g + 4*(nt&1) + r
    // pack P into K=32 A-frags ----
    u32x4 pa32[2][2];
#pragma unroll
    for (int qh = 0; qh < 2; ++qh) {
#pragma unroll
      for (int nt = 0; nt < 4; ++nt) {
        const float tg = (float)(t0 + 32 * (nt >> 1) + 4 * (nt & 1) + 8 * g);
        float p[4];
#pragma unroll
        for (int r = 0; r < 4; ++r) {
          const float d = srowf[qh] - (tg + (float)r);
          p[r] = vexp2(fmaf(-slope2, fabsf(d), sa[qh][nt][r]));
          l_part[qh] += p[r];
        }
        pa32[qh][nt >> 1][(nt & 1) * 2 + 0] = cvtpk(p[0], p[1]);
        pa32[qh][nt >> 1][(nt & 1) * 2 + 1] = cvtpk(p[2], p[3]);
      }
    }

    // ---- O += P V : 16 x v_mfma_16x16x32, V via b128 (vT rows contiguous) --
    __builtin_amdgcn_s_setprio(1);
#pragma unroll
    for (int ntd = 0; ntd < 4; ++ntd) {
#pragma unroll
      for (int s = 0; s < 2; ++s) {
        bf16x8 vb = ld8s(&Vs[cur][kaddr(c + 16 * ntd, 4 * s + g)]);
        accO[0][ntd] = __builtin_amdgcn_mfma_f32_16x16x32_bf16(
            __builtin_bit_cast(bf16x8, pa32[0][s]), vb, accO[0][ntd], 0, 0, 0);
        accO[1][ntd] = __builtin_amdgcn_mfma_f32_16x16x32_bf16(
            __builtin_bit_cast(bf16x8, pa32[1][s]), vb, accO[1][ntd], 0, 0, 0);
      }
    }
    __builtin_amdgcn_s_setprio(0);

    __syncthreads();
    cur ^= 1;
  }

  // ---- row-sum reduce + redistribute + store ----
  float linv[2][4];
#pragma unroll
  for (int qh = 0; qh < 2; ++qh) {
    float rs = l_part[qh];
    rs += __shfl_xor(rs, 16, 64);
    rs += __shfl_xor(rs, 32, 64);
    const float inv = 1.0f / rs;
#pragma unroll
    for (int r = 0; r < 4; ++r)
      linv[qh][r] = __shfl(inv, g * 4 + r, 64);
  }

#pragma unroll
  for (int qh = 0; qh < 2; ++qh)
#pragma unroll
    for (int r = 0; r < 4; ++r) {
      const int srow = sb + qh * 16 + g * 4 + r;
      const size_t ob = (size_t)(CU[b] + srow) * 768 + h * 64;
#pragma unroll
      for (int ntd = 0; ntd < 4; ++ntd)
        out[ob + ntd * 16 + c] = accO[qh][ntd][r] * linv[qh][r];
    }
}

extern "C" void kernel_launch(void* const* d_in, const int* in_sizes, int n_in,
                              void* d_out, int out_size, void* d_ws, size_t ws_size,
                              hipStream_t stream) {
  const float* hidden = (const float*)d_in[0];
  const float* Wqkv_w = (const float*)d_in[1];
  const float* Wqkv_b = (const float*)d_in[2];

  constexpr size_t NA_PAD = (size_t)6656 * 768;
  constexpr size_t NW = (size_t)2304 * 768;
  constexpr size_t NP = (size_t)8 * 12 * 1024 * 64;

  short* hb   = (short*)d_ws;
  short* wb   = hb + NA_PAD;
  short* qws  = wb + NW;
  short* kws  = qws + NP;
  short* vtws = kws + NP;

  convert_in<<<dim3(2048), 256, 0, stream>>>(hidden, Wqkv_w, hb, wb);
  qkv_gemm<<<dim3(26, 18), 256, 0, stream>>>(hb, wb, Wqkv_b, qws, kws, vtws);
  attn<<<dim3(51, 12), 256, 0, stream>>>(qws, kws, vtws, (float*)d_out);
}

// Round 25
// 69.944 us; speedup vs baseline: 1.1128x; 1.1063x over previous
//
#include <hip/hip_runtime.h>
#include <hip/hip_bf16.h>
#include <stdint.h>

// Problem constants (fixed by setup_inputs)
// B=8, S=1024, HID=768, NH=12, D=64, total=6528
// LENGTHS = {1024,896,768,640,1024,512,768,896}  (all multiples of 128)
//
// R25 = r22 (77.09us, reproduced 3x) + ONE delta: attn tail scheduling.
// 612 blocks at 2/CU residency = 512 slots -> 100-block tail round. Grid
// swapped to (12 heads, 51 qtiles) [x fastest in HSA linearization] and the
// qtile index routed through the longest-first permutation, so the tail
// round holds the SHORTEST jobs (Lb=512/640) instead of average ones.
// Pure bijective block reordering: zero resource/correctness change.
// GEMM/convert byte-identical to r22.

typedef __attribute__((ext_vector_type(8))) __bf16 bf16x8;
typedef __attribute__((ext_vector_type(8))) short short8;
typedef __attribute__((ext_vector_type(4))) short short4v;
typedef __attribute__((ext_vector_type(4))) float f32x4;
typedef __attribute__((ext_vector_type(4))) unsigned int u32x4;
typedef unsigned int u32;

#define AS1 __attribute__((address_space(1)))
#define AS3 __attribute__((address_space(3)))

static __device__ __forceinline__ unsigned short f2bf(float x) {
  unsigned u = __builtin_bit_cast(unsigned, x);
  u += 0x7fffu + ((u >> 16) & 1u);   // RTNE
  return (unsigned short)(u >> 16);
}
static __device__ __forceinline__ bf16x8 ld8s(const short* p) {
  return __builtin_bit_cast(bf16x8, *(const short8*)p);
}
static __device__ __forceinline__ u32 cvtpk(float lo, float hi) {
  u32 r;
  asm("v_cvt_pk_bf16_f32 %0, %1, %2" : "=v"(r) : "v"(lo), "v"(hi));
  return r;
}
// single-instruction 2^x (flush-to-zero below -126: fine for masked keys)
static __device__ __forceinline__ float vexp2(float x) {
  float r;
  asm("v_exp_f32 %0, %1" : "=v"(r) : "v"(x));
  return r;
}

__device__ const float g_slope[12] = {
  0.6299605249f, 0.3968502630f, 0.25f,          0.1574901312f,
  0.0992125657f, 0.0625f,       0.0393725328f,  0.0248031414f,
  0.015625f,     0.0098431332f, 0.0062007854f,  0.00390625f
};

// longest-first qtile order: b0,b4 (L=1024), b1,b7 (896), b2,b6 (768),
// b3 (640), b5 (512). Shortest jobs land in the dispatch tail.
__device__ const unsigned char g_gqperm[51] = {
  0,1,2,3,4,5,6,7, 26,27,28,29,30,31,32,33, 8,9,10,11,12,13,14,
  44,45,46,47,48,49,50, 15,16,17,18,19,20, 38,39,40,41,42,43,
  21,22,23,24,25, 34,35,36,37
};

// ---------------------------------------------------------------------------
// Kernel 0: f32 -> bf16 streaming convert of hidden & Wqkv (r22 exact).
// ---------------------------------------------------------------------------
__global__ __launch_bounds__(256) void convert_in(
    const float* __restrict__ hidden, const float* __restrict__ W,
    short* __restrict__ hb, short* __restrict__ wb)
{
  constexpr int NA = 6528 * 768;
  constexpr int NW = 2304 * 768;
  const int tot4 = (NA + NW) / 4;
  for (int idx = blockIdx.x * 256 + threadIdx.x; idx < tot4; idx += gridDim.x * 256) {
    const int e0 = idx * 4;
    const float* src; short* dst; int off;
    if (e0 < NA) { src = hidden; dst = hb; off = e0; }
    else         { src = W;      dst = wb; off = e0 - NA; }
    f32x4 v = *((const f32x4*)(src + off));
    short4v o;
    o[0] = (short)f2bf(v[0]); o[1] = (short)f2bf(v[1]);
    o[2] = (short)f2bf(v[2]); o[3] = (short)f2bf(v[3]);
    *(short4v*)(dst + off) = o;
  }
}

// ---------------------------------------------------------------------------
// Kernel 1: qkv GEMM (r22 exact). BM=256 BN=128 BK=64, 12 K-steps, 8-chunk
// XOR swizzle, 2-phase __syncthreads dbuf. q pre-scaled 0.125*log2e.
// ---------------------------------------------------------------------------
__global__ __launch_bounds__(256, 2) void qkv_gemm(
    const short* __restrict__ A, const short* __restrict__ W,
    const float* __restrict__ bias,
    short* __restrict__ qws, short* __restrict__ kws, short* __restrict__ vtws)
{
  constexpr int CUb[9] = {0,1024,1920,2688,3328,4352,4864,5632,6528};
  __shared__ __align__(16) short As[256 * 64];   // 32 KB
  __shared__ __align__(16) short Bs[128 * 64];   // 16 KB
  const int tid  = threadIdx.x;
  const int lane = tid & 63, w = tid >> 6;
  const int g = lane >> 4, c = lane & 15;
  const int wm = w >> 1, wn = w & 1;
  const int bm = blockIdx.x, bn = blockIdx.y;

  const short* Ab = A + (size_t)bm * 256 * 768;
  const short* Wb = W + (size_t)bn * 128 * 768;

  f32x4 acc[8][4] = {};
  const int sR8 = lane >> 3;
  const int sC8 = (lane & 7) ^ sR8;

  for (int kt = 0; kt < 12; ++kt) {
    if (kt) __syncthreads();
#pragma unroll
    for (int i = 0; i < 8; ++i) {        // A: 32 insts (8/wave)
      const int j = w * 8 + i;
      const AS1 unsigned int* ga =
        (const AS1 unsigned int*)(Ab + (size_t)(j * 8 + sR8) * 768 + kt * 64 + sC8 * 8);
      __builtin_amdgcn_global_load_lds(ga, (AS3 unsigned int*)&As[j * 512], 16, 0, 0);
    }
#pragma unroll
    for (int i = 0; i < 4; ++i) {        // B: 16 insts (4/wave)
      const int j = w * 4 + i;
      const AS1 unsigned int* gb =
        (const AS1 unsigned int*)(Wb + (size_t)(j * 8 + sR8) * 768 + kt * 64 + sC8 * 8);
      __builtin_amdgcn_global_load_lds(gb, (AS3 unsigned int*)&Bs[j * 512], 16, 0, 0);
    }
    __syncthreads();

#pragma unroll
    for (int kh = 0; kh < 2; ++kh) {
      const int xg = (((kh * 4 + g) ^ (c & 7)) << 3);
      bf16x8 bfr[4];
#pragma unroll
      for (int nt = 0; nt < 4; ++nt)
        bfr[nt] = ld8s(&Bs[(wn * 64 + nt * 16 + c) * 64 + xg]);
#pragma unroll
      for (int mt = 0; mt < 8; ++mt) {
        bf16x8 af = ld8s(&As[(wm * 128 + mt * 16 + c) * 64 + xg]);
#pragma unroll
        for (int nt = 0; nt < 4; ++nt)
          acc[mt][nt] = __builtin_amdgcn_mfma_f32_16x16x32_bf16(af, bfr[nt], acc[mt][nt], 0, 0, 0);
      }
    }
  }

  const int row0 = bm * 256 + wm * 128;
  if (row0 >= 6528) return;
  int b = 0;
#pragma unroll
  for (int i = 0; i < 8; ++i) if (row0 >= CUb[i + 1]) b = i + 1;
  const int col0  = bn * 128 + wn * 64;
  const int which = col0 / 768;
  const int hh    = (col0 % 768) / 64;
  const int srow0 = row0 - CUb[b];

  float bb[4];
#pragma unroll
  for (int nt = 0; nt < 4; ++nt) bb[nt] = bias[col0 + nt * 16 + c];

  if (which < 2) {
    // q pre-scaled by (1/8)*log2(e) so attn's softmax is a bare fma+v_exp
    const float sc = which ? 1.0f : 0.18033688011112042f;
    short* dst = (which ? kws : qws) + (size_t)(b * 12 + hh) * 1024 * 64;
#pragma unroll
    for (int mt = 0; mt < 8; ++mt)
#pragma unroll
      for (int nt = 0; nt < 4; ++nt)
#pragma unroll
        for (int r = 0; r < 4; ++r) {
          const int s = srow0 + mt * 16 + g * 4 + r;
          dst[(size_t)s * 64 + nt * 16 + c] = (short)f2bf((acc[mt][nt][r] + bb[nt]) * sc);
        }
  } else {
    short* dst = vtws + (size_t)(b * 12 + hh) * 64 * 1024;
#pragma unroll
    for (int mt = 0; mt < 8; ++mt)
#pragma unroll
      for (int nt = 0; nt < 4; ++nt) {
        const int s = srow0 + mt * 16 + g * 4;
        short4v pk;
        pk[0] = (short)f2bf(acc[mt][nt][0] + bb[nt]);
        pk[1] = (short)f2bf(acc[mt][nt][1] + bb[nt]);
        pk[2] = (short)f2bf(acc[mt][nt][2] + bb[nt]);
        pk[3] = (short)f2bf(acc[mt][nt][3] + bb[nt]);
        *(short4v*)&dst[(size_t)(nt * 16 + c) * 1024 + s] = pk;
      }
  }
}

// ---------------------------------------------------------------------------
// Kernel 2: flash attention (r22 structure) — swapped-QK^T with bit-permuted
// K rows, in-register P, K=32 PV, KVBLK=64 dbuf. Deltas: grid (12,51) with
// x=head, y=qtile; longest-first qtile permutation.
// ---------------------------------------------------------------------------
__global__ __launch_bounds__(256, 2) void attn(
    const short* __restrict__ qws, const short* __restrict__ kws,
    const short* __restrict__ vtws, float* __restrict__ out)
{
  constexpr int CU[9]  = {0,1024,1920,2688,3328,4352,4864,5632,6528};
  constexpr int CQT[9] = {0,8,15,21,26,34,38,44,51};
  __shared__ __align__(16) short Ks[2][64 * 64];
  __shared__ __align__(16) short Vs[2][64 * 64];
  const int tid = threadIdx.x, lane = tid & 63, w = tid >> 6;
  const int g = lane >> 4, c = lane & 15;
  const int h = blockIdx.x;                      // x = head (fastest)
  const int gq = g_gqperm[blockIdx.y];           // y = qtile, longest-first
  int b = 0;
#pragma unroll
  for (int i = 0; i < 8; ++i) if (gq >= CQT[i + 1]) b = i + 1;
  const int qt = gq - CQT[b];
  const int Lb = CU[b + 1] - CU[b];
  const int sb = qt * 128 + w * 32;
  const size_t bh = (size_t)(b * 12 + h) * 1024 * 64;
  const short* qp = qws + bh;
  const short* kp = kws + bh;
  const short* vp = vtws + bh;
  const float slope2 = g_slope[h] * 1.4426950408889634f;   // slope * log2(e)

  const int sRow = lane >> 3;
  const int sChk = (lane & 7) ^ (sRow & 7);

  bf16x8 qf[2][2];
#pragma unroll
  for (int qh = 0; qh < 2; ++qh)
#pragma unroll
    for (int ks = 0; ks < 2; ++ks)
      qf[qh][ks] = ld8s(qp + (size_t)(sb + qh * 16 + c) * 64 + ks * 32 + g * 8);

  float srowf[2];
#pragma unroll
  for (int qh = 0; qh < 2; ++qh) srowf[qh] = (float)(sb + qh * 16 + c);

  f32x4 accO[2][4] = {};
  float l_part[2] = {};

  auto kaddr = [&](int row, int chunk) { return row * 64 + ((chunk ^ (row & 7)) << 3); };
  // K row bit-permutation (r22): LDS row p holds K[t0 + fperm(p)] so QK's
  // C-layout gives k = 32*(nt>>1) + 8g + 4*(nt&1) + r (16x16x32 A-frag).
  auto fperm = [&](int p) {
    return (p & 32) | (((p >> 2) & 3) << 3) | (((p >> 4) & 1) << 2) | (p & 3);
  };

  auto stageKV = [&](int t, int buf) {
#pragma unroll
    for (int i = 0; i < 2; ++i) {
      const int j = w * 2 + i;
      const int dRow = j * 8 + sRow;
      const AS1 unsigned int* gk =
        (const AS1 unsigned int*)(kp + (size_t)(t + fperm(dRow)) * 64 + sChk * 8);
      __builtin_amdgcn_global_load_lds(gk, (AS3 unsigned int*)&Ks[buf][j * 512], 16, 0, 0);
      const AS1 unsigned int* gv =
        (const AS1 unsigned int*)(vp + (size_t)dRow * 1024 + t + sChk * 8);
      __builtin_amdgcn_global_load_lds(gv, (AS3 unsigned int*)&Vs[buf][j * 512], 16, 0, 0);
    }
  };

  // ---- prologue: stage tile 0 into buf 0 ----
  stageKV(0, 0);
  __syncthreads();

  int cur = 0;
  for (int t0 = 0; t0 < Lb; t0 += 64) {
    if (t0 + 64 < Lb) stageKV(t0 + 64, cur ^ 1);

    // ---- S^T = K Q (rows relabeled by fperm) ----
    f32x4 sa[2][4];
    __builtin_amdgcn_s_setprio(1);
#pragma unroll
    for (int nt = 0; nt < 4; ++nt) {
      bf16x8 kf0 = ld8s(&Ks[cur][kaddr(nt * 16 + c, g)]);
      bf16x8 kf1 = ld8s(&Ks[cur][kaddr(nt * 16 + c, 4 + g)]);
#pragma unroll
      for (int qh = 0; qh < 2; ++qh) {
        f32x4 z = {};
        z = __builtin_amdgcn_mfma_f32_16x16x32_bf16(kf0, qf[qh][0], z, 0, 0, 0);
        sa[qh][nt] = __builtin_amdgcn_mfma_f32_16x16x32_bf16(kf1, qf[qh][1], z, 0, 0, 0);
      }
    }
    __builtin_amdgcn_s_setprio(0);

    // ---- softmax: sa[qh][nt][r] is k = t0 + 32*(nt>>1) + 8g + 4*(nt&1) + r
    // pack P into K=32 A-frags ----
    u32x4 pa32[2][2];
#pragma unroll
    for (int qh = 0; qh < 2; ++qh) {
#pragma unroll
      for (int nt = 0; nt < 4; ++nt) {
        const float tg = (float)(t0 + 32 * (nt >> 1) + 4 * (nt & 1) + 8 * g);
        float p[4];
#pragma unroll
        for (int r = 0; r < 4; ++r) {
          const float d = srowf[qh] - (tg + (float)r);
          p[r] = vexp2(fmaf(-slope2, fabsf(d), sa[qh][nt][r]));
          l_part[qh] += p[r];
        }
        pa32[qh][nt >> 1][(nt & 1) * 2 + 0] = cvtpk(p[0], p[1]);
        pa32[qh][nt >> 1][(nt & 1) * 2 + 1] = cvtpk(p[2], p[3]);
      }
    }

    // ---- O += P V : 16 x v_mfma_16x16x32, V via b128 (vT rows contiguous) --
    __builtin_amdgcn_s_setprio(1);
#pragma unroll
    for (int ntd = 0; ntd < 4; ++ntd) {
#pragma unroll
      for (int s = 0; s < 2; ++s) {
        bf16x8 vb = ld8s(&Vs[cur][kaddr(c + 16 * ntd, 4 * s + g)]);
        accO[0][ntd] = __builtin_amdgcn_mfma_f32_16x16x32_bf16(
            __builtin_bit_cast(bf16x8, pa32[0][s]), vb, accO[0][ntd], 0, 0, 0);
        accO[1][ntd] = __builtin_amdgcn_mfma_f32_16x16x32_bf16(
            __builtin_bit_cast(bf16x8, pa32[1][s]), vb, accO[1][ntd], 0, 0, 0);
      }
    }
    __builtin_amdgcn_s_setprio(0);

    __syncthreads();
    cur ^= 1;
  }

  // ---- row-sum reduce + redistribute + store ----
  float linv[2][4];
#pragma unroll
  for (int qh = 0; qh < 2; ++qh) {
    float rs = l_part[qh];
    rs += __shfl_xor(rs, 16, 64);
    rs += __shfl_xor(rs, 32, 64);
    const float inv = 1.0f / rs;
#pragma unroll
    for (int r = 0; r < 4; ++r)
      linv[qh][r] = __shfl(inv, g * 4 + r, 64);
  }

#pragma unroll
  for (int qh = 0; qh < 2; ++qh)
#pragma unroll
    for (int r = 0; r < 4; ++r) {
      const int srow = sb + qh * 16 + g * 4 + r;
      const size_t ob = (size_t)(CU[b] + srow) * 768 + h * 64;
#pragma unroll
      for (int ntd = 0; ntd < 4; ++ntd)
        out[ob + ntd * 16 + c] = accO[qh][ntd][r] * linv[qh][r];
    }
}

extern "C" void kernel_launch(void* const* d_in, const int* in_sizes, int n_in,
                              void* d_out, int out_size, void* d_ws, size_t ws_size,
                              hipStream_t stream) {
  const float* hidden = (const float*)d_in[0];
  const float* Wqkv_w = (const float*)d_in[1];
  const float* Wqkv_b = (const float*)d_in[2];

  constexpr size_t NA_PAD = (size_t)6656 * 768;
  constexpr size_t NW = (size_t)2304 * 768;
  constexpr size_t NP = (size_t)8 * 12 * 1024 * 64;

  short* hb   = (short*)d_ws;
  short* wb   = hb + NA_PAD;
  short* qws  = wb + NW;
  short* kws  = qws + NP;
  short* vtws = kws + NP;

  convert_in<<<dim3(2048), 256, 0, stream>>>(hidden, Wqkv_w, hb, wb);
  qkv_gemm<<<dim3(26, 18), 256, 0, stream>>>(hb, wb, Wqkv_b, qws, kws, vtws);
  attn<<<dim3(12, 51), 256, 0, stream>>>(qws, kws, vtws, (float*)d_out);
}

// Round 26
// 69.712 us; speedup vs baseline: 1.1165x; 1.0033x over previous
//
#include <hip/hip_runtime.h>
#include <hip/hip_bf16.h>
#include <stdint.h>

// Problem constants (fixed by setup_inputs)
// B=8, S=1024, HID=768, NH=12, D=64, total=6528
// LENGTHS = {1024,896,768,640,1024,512,768,896}  (all multiples of 128)
//
// FINAL = r25 EXACT (best: 69.94us; re-validation run).
//   convert: streaming f32->bf16 (~8us, HBM-bound)
//   gemm: BM=256 BN=128 BK=64 (12 K-steps), gload_lds w16, 8-chunk XOR
//         swizzle, 2-phase __syncthreads dbuf, q pre-scaled 0.125*log2e (~27us)
//   attn: KVBLK=64 dbuf; swapped-QK^T with bit-permuted K rows so the QK
//         C-layout IS the 16x16x32 A-frag layout -> in-register P
//         (v_cvt_pk_bf16_f32) feeds K=32 PV MFMA; fixed-max base-2 softmax,
//         1-inst v_exp_f32; deferred row-sum; grid (12 heads, 51 qtiles)
//         with longest-first qtile permutation (LPT scheduling, -7us).

typedef __attribute__((ext_vector_type(8))) __bf16 bf16x8;
typedef __attribute__((ext_vector_type(8))) short short8;
typedef __attribute__((ext_vector_type(4))) short short4v;
typedef __attribute__((ext_vector_type(4))) float f32x4;
typedef __attribute__((ext_vector_type(4))) unsigned int u32x4;
typedef unsigned int u32;

#define AS1 __attribute__((address_space(1)))
#define AS3 __attribute__((address_space(3)))

static __device__ __forceinline__ unsigned short f2bf(float x) {
  unsigned u = __builtin_bit_cast(unsigned, x);
  u += 0x7fffu + ((u >> 16) & 1u);   // RTNE
  return (unsigned short)(u >> 16);
}
static __device__ __forceinline__ bf16x8 ld8s(const short* p) {
  return __builtin_bit_cast(bf16x8, *(const short8*)p);
}
static __device__ __forceinline__ u32 cvtpk(float lo, float hi) {
  u32 r;
  asm("v_cvt_pk_bf16_f32 %0, %1, %2" : "=v"(r) : "v"(lo), "v"(hi));
  return r;
}
// single-instruction 2^x (flush-to-zero below -126: fine for masked keys)
static __device__ __forceinline__ float vexp2(float x) {
  float r;
  asm("v_exp_f32 %0, %1" : "=v"(r) : "v"(x));
  return r;
}

__device__ const float g_slope[12] = {
  0.6299605249f, 0.3968502630f, 0.25f,          0.1574901312f,
  0.0992125657f, 0.0625f,       0.0393725328f,  0.0248031414f,
  0.015625f,     0.0098431332f, 0.0062007854f,  0.00390625f
};

// longest-first qtile order: b0,b4 (L=1024), b1,b7 (896), b2,b6 (768),
// b3 (640), b5 (512). Shortest jobs land in the dispatch tail (LPT).
__device__ const unsigned char g_gqperm[51] = {
  0,1,2,3,4,5,6,7, 26,27,28,29,30,31,32,33, 8,9,10,11,12,13,14,
  44,45,46,47,48,49,50, 15,16,17,18,19,20, 38,39,40,41,42,43,
  21,22,23,24,25, 34,35,36,37
};

// ---------------------------------------------------------------------------
// Kernel 0: f32 -> bf16 streaming convert of hidden & Wqkv.
// ---------------------------------------------------------------------------
__global__ __launch_bounds__(256) void convert_in(
    const float* __restrict__ hidden, const float* __restrict__ W,
    short* __restrict__ hb, short* __restrict__ wb)
{
  constexpr int NA = 6528 * 768;
  constexpr int NW = 2304 * 768;
  const int tot4 = (NA + NW) / 4;
  for (int idx = blockIdx.x * 256 + threadIdx.x; idx < tot4; idx += gridDim.x * 256) {
    const int e0 = idx * 4;
    const float* src; short* dst; int off;
    if (e0 < NA) { src = hidden; dst = hb; off = e0; }
    else         { src = W;      dst = wb; off = e0 - NA; }
    f32x4 v = *((const f32x4*)(src + off));
    short4v o;
    o[0] = (short)f2bf(v[0]); o[1] = (short)f2bf(v[1]);
    o[2] = (short)f2bf(v[2]); o[3] = (short)f2bf(v[3]);
    *(short4v*)(dst + off) = o;
  }
}

// ---------------------------------------------------------------------------
// Kernel 1: qkv GEMM. BM=256 BN=128 BK=64; 4 waves (2M x 2N), wave tile
// 128x64, acc[8][4]. 8-chunk-XOR swizzled LDS (pre-swizzled gload_lds source
// + XOR'd ds_read_b128), 2-phase __syncthreads dbuf, 12 K-steps.
// q PRE-SCALED by 0.125*log2e. Pad rows >= 6528: stores skipped.
// ---------------------------------------------------------------------------
__global__ __launch_bounds__(256, 2) void qkv_gemm(
    const short* __restrict__ A, const short* __restrict__ W,
    const float* __restrict__ bias,
    short* __restrict__ qws, short* __restrict__ kws, short* __restrict__ vtws)
{
  constexpr int CUb[9] = {0,1024,1920,2688,3328,4352,4864,5632,6528};
  __shared__ __align__(16) short As[256 * 64];   // 32 KB
  __shared__ __align__(16) short Bs[128 * 64];   // 16 KB
  const int tid  = threadIdx.x;
  const int lane = tid & 63, w = tid >> 6;
  const int g = lane >> 4, c = lane & 15;
  const int wm = w >> 1, wn = w & 1;
  const int bm = blockIdx.x, bn = blockIdx.y;

  const short* Ab = A + (size_t)bm * 256 * 768;
  const short* Wb = W + (size_t)bn * 128 * 768;

  f32x4 acc[8][4] = {};
  const int sR8 = lane >> 3;
  const int sC8 = (lane & 7) ^ sR8;

  for (int kt = 0; kt < 12; ++kt) {
    if (kt) __syncthreads();
#pragma unroll
    for (int i = 0; i < 8; ++i) {        // A: 32 insts (8/wave)
      const int j = w * 8 + i;
      const AS1 unsigned int* ga =
        (const AS1 unsigned int*)(Ab + (size_t)(j * 8 + sR8) * 768 + kt * 64 + sC8 * 8);
      __builtin_amdgcn_global_load_lds(ga, (AS3 unsigned int*)&As[j * 512], 16, 0, 0);
    }
#pragma unroll
    for (int i = 0; i < 4; ++i) {        // B: 16 insts (4/wave)
      const int j = w * 4 + i;
      const AS1 unsigned int* gb =
        (const AS1 unsigned int*)(Wb + (size_t)(j * 8 + sR8) * 768 + kt * 64 + sC8 * 8);
      __builtin_amdgcn_global_load_lds(gb, (AS3 unsigned int*)&Bs[j * 512], 16, 0, 0);
    }
    __syncthreads();

#pragma unroll
    for (int kh = 0; kh < 2; ++kh) {
      const int xg = (((kh * 4 + g) ^ (c & 7)) << 3);
      bf16x8 bfr[4];
#pragma unroll
      for (int nt = 0; nt < 4; ++nt)
        bfr[nt] = ld8s(&Bs[(wn * 64 + nt * 16 + c) * 64 + xg]);
#pragma unroll
      for (int mt = 0; mt < 8; ++mt) {
        bf16x8 af = ld8s(&As[(wm * 128 + mt * 16 + c) * 64 + xg]);
#pragma unroll
        for (int nt = 0; nt < 4; ++nt)
          acc[mt][nt] = __builtin_amdgcn_mfma_f32_16x16x32_bf16(af, bfr[nt], acc[mt][nt], 0, 0, 0);
      }
    }
  }

  const int row0 = bm * 256 + wm * 128;
  if (row0 >= 6528) return;
  int b = 0;
#pragma unroll
  for (int i = 0; i < 8; ++i) if (row0 >= CUb[i + 1]) b = i + 1;
  const int col0  = bn * 128 + wn * 64;
  const int which = col0 / 768;
  const int hh    = (col0 % 768) / 64;
  const int srow0 = row0 - CUb[b];

  float bb[4];
#pragma unroll
  for (int nt = 0; nt < 4; ++nt) bb[nt] = bias[col0 + nt * 16 + c];

  if (which < 2) {
    // q pre-scaled by (1/8)*log2(e) so attn's softmax is a bare fma+v_exp
    const float sc = which ? 1.0f : 0.18033688011112042f;
    short* dst = (which ? kws : qws) + (size_t)(b * 12 + hh) * 1024 * 64;
#pragma unroll
    for (int mt = 0; mt < 8; ++mt)
#pragma unroll
      for (int nt = 0; nt < 4; ++nt)
#pragma unroll
        for (int r = 0; r < 4; ++r) {
          const int s = srow0 + mt * 16 + g * 4 + r;
          dst[(size_t)s * 64 + nt * 16 + c] = (short)f2bf((acc[mt][nt][r] + bb[nt]) * sc);
        }
  } else {
    short* dst = vtws + (size_t)(b * 12 + hh) * 64 * 1024;
#pragma unroll
    for (int mt = 0; mt < 8; ++mt)
#pragma unroll
      for (int nt = 0; nt < 4; ++nt) {
        const int s = srow0 + mt * 16 + g * 4;
        short4v pk;
        pk[0] = (short)f2bf(acc[mt][nt][0] + bb[nt]);
        pk[1] = (short)f2bf(acc[mt][nt][1] + bb[nt]);
        pk[2] = (short)f2bf(acc[mt][nt][2] + bb[nt]);
        pk[3] = (short)f2bf(acc[mt][nt][3] + bb[nt]);
        *(short4v*)&dst[(size_t)(nt * 16 + c) * 1024 + s] = pk;
      }
  }
}

// ---------------------------------------------------------------------------
// Kernel 2: flash attention — swapped-QK^T with bit-permuted K rows,
// in-register P, K=32 PV, KVBLK=64 dbuf. Grid (12 heads, 51 qtiles) with
// longest-first qtile permutation.
// ---------------------------------------------------------------------------
__global__ __launch_bounds__(256, 2) void attn(
    const short* __restrict__ qws, const short* __restrict__ kws,
    const short* __restrict__ vtws, float* __restrict__ out)
{
  constexpr int CU[9]  = {0,1024,1920,2688,3328,4352,4864,5632,6528};
  constexpr int CQT[9] = {0,8,15,21,26,34,38,44,51};
  __shared__ __align__(16) short Ks[2][64 * 64];
  __shared__ __align__(16) short Vs[2][64 * 64];
  const int tid = threadIdx.x, lane = tid & 63, w = tid >> 6;
  const int g = lane >> 4, c = lane & 15;
  const int h = blockIdx.x;                      // x = head (fastest)
  const int gq = g_gqperm[blockIdx.y];           // y = qtile, longest-first
  int b = 0;
#pragma unroll
  for (int i = 0; i < 8; ++i) if (gq >= CQT[i + 1]) b = i + 1;
  const int qt = gq - CQT[b];
  const int Lb = CU[b + 1] - CU[b];
  const int sb = qt * 128 + w * 32;
  const size_t bh = (size_t)(b * 12 + h) * 1024 * 64;
  const short* qp = qws + bh;
  const short* kp = kws + bh;
  const short* vp = vtws + bh;
  const float slope2 = g_slope[h] * 1.4426950408889634f;   // slope * log2(e)

  const int sRow = lane >> 3;
  const int sChk = (lane & 7) ^ (sRow & 7);

  bf16x8 qf[2][2];
#pragma unroll
  for (int qh = 0; qh < 2; ++qh)
#pragma unroll
    for (int ks = 0; ks < 2; ++ks)
      qf[qh][ks] = ld8s(qp + (size_t)(sb + qh * 16 + c) * 64 + ks * 32 + g * 8);

  float srowf[2];
#pragma unroll
  for (int qh = 0; qh < 2; ++qh) srowf[qh] = (float)(sb + qh * 16 + c);

  f32x4 accO[2][4] = {};
  float l_part[2] = {};

  auto kaddr = [&](int row, int chunk) { return row * 64 + ((chunk ^ (row & 7)) << 3); };
  // K row bit-permutation: LDS row p holds K[t0 + fperm(p)] so QK's C-layout
  // gives k = 32*(nt>>1) + 8g + 4*(nt&1) + r (the 16x16x32 A-frag layout).
  auto fperm = [&](int p) {
    return (p & 32) | (((p >> 2) & 3) << 3) | (((p >> 4) & 1) << 2) | (p & 3);
  };

  auto stageKV = [&](int t, int buf) {
#pragma unroll
    for (int i = 0; i < 2; ++i) {
      const int j = w * 2 + i;
      const int dRow = j * 8 + sRow;
      const AS1 unsigned int* gk =
        (const AS1 unsigned int*)(kp + (size_t)(t + fperm(dRow)) * 64 + sChk * 8);
      __builtin_amdgcn_global_load_lds(gk, (AS3 unsigned int*)&Ks[buf][j * 512], 16, 0, 0);
      const AS1 unsigned int* gv =
        (const AS1 unsigned int*)(vp + (size_t)dRow * 1024 + t + sChk * 8);
      __builtin_amdgcn_global_load_lds(gv, (AS3 unsigned int*)&Vs[buf][j * 512], 16, 0, 0);
    }
  };

  // ---- prologue: stage tile 0 into buf 0 ----
  stageKV(0, 0);
  __syncthreads();

  int cur = 0;
  for (int t0 = 0; t0 < Lb; t0 += 64) {
    if (t0 + 64 < Lb) stageKV(t0 + 64, cur ^ 1);

    // ---- S^T = K Q (rows relabeled by fperm) ----
    f32x4 sa[2][4];
    __builtin_amdgcn_s_setprio(1);
#pragma unroll
    for (int nt = 0; nt < 4; ++nt) {
      bf16x8 kf0 = ld8s(&Ks[cur][kaddr(nt * 16 + c, g)]);
      bf16x8 kf1 = ld8s(&Ks[cur][kaddr(nt * 16 + c, 4 + g)]);
#pragma unroll
      for (int qh = 0; qh < 2; ++qh) {
        f32x4 z = {};
        z = __builtin_amdgcn_mfma_f32_16x16x32_bf16(kf0, qf[qh][0], z, 0, 0, 0);
        sa[qh][nt] = __builtin_amdgcn_mfma_f32_16x16x32_bf16(kf1, qf[qh][1], z, 0, 0, 0);
      }
    }
    __builtin_amdgcn_s_setprio(0);

    // ---- softmax: sa[qh][nt][r] is k = t0 + 32*(nt>>1) + 8g + 4*(nt&1) + r
    // pack P into K=32 A-frags ----
    u32x4 pa32[2][2];
#pragma unroll
    for (int qh = 0; qh < 2; ++qh) {
#pragma unroll
      for (int nt = 0; nt < 4; ++nt) {
        const float tg = (float)(t0 + 32 * (nt >> 1) + 4 * (nt & 1) + 8 * g);
        float p[4];
#pragma unroll
        for (int r = 0; r < 4; ++r) {
          const float d = srowf[qh] - (tg + (float)r);
          p[r] = vexp2(fmaf(-slope2, fabsf(d), sa[qh][nt][r]));
          l_part[qh] += p[r];
        }
        pa32[qh][nt >> 1][(nt & 1) * 2 + 0] = cvtpk(p[0], p[1]);
        pa32[qh][nt >> 1][(nt & 1) * 2 + 1] = cvtpk(p[2], p[3]);
      }
    }

    // ---- O += P V : 16 x v_mfma_16x16x32, V via b128 (vT rows contiguous) --
    __builtin_amdgcn_s_setprio(1);
#pragma unroll
    for (int ntd = 0; ntd < 4; ++ntd) {
#pragma unroll
      for (int s = 0; s < 2; ++s) {
        bf16x8 vb = ld8s(&Vs[cur][kaddr(c + 16 * ntd, 4 * s + g)]);
        accO[0][ntd] = __builtin_amdgcn_mfma_f32_16x16x32_bf16(
            __builtin_bit_cast(bf16x8, pa32[0][s]), vb, accO[0][ntd], 0, 0, 0);
        accO[1][ntd] = __builtin_amdgcn_mfma_f32_16x16x32_bf16(
            __builtin_bit_cast(bf16x8, pa32[1][s]), vb, accO[1][ntd], 0, 0, 0);
      }
    }
    __builtin_amdgcn_s_setprio(0);

    __syncthreads();
    cur ^= 1;
  }

  // ---- row-sum reduce + redistribute + store ----
  float linv[2][4];
#pragma unroll
  for (int qh = 0; qh < 2; ++qh) {
    float rs = l_part[qh];
    rs += __shfl_xor(rs, 16, 64);
    rs += __shfl_xor(rs, 32, 64);
    const float inv = 1.0f / rs;
#pragma unroll
    for (int r = 0; r < 4; ++r)
      linv[qh][r] = __shfl(inv, g * 4 + r, 64);
  }

#pragma unroll
  for (int qh = 0; qh < 2; ++qh)
#pragma unroll
    for (int r = 0; r < 4; ++r) {
      const int srow = sb + qh * 16 + g * 4 + r;
      const size_t ob = (size_t)(CU[b] + srow) * 768 + h * 64;
#pragma unroll
      for (int ntd = 0; ntd < 4; ++ntd)
        out[ob + ntd * 16 + c] = accO[qh][ntd][r] * linv[qh][r];
    }
}

extern "C" void kernel_launch(void* const* d_in, const int* in_sizes, int n_in,
                              void* d_out, int out_size, void* d_ws, size_t ws_size,
                              hipStream_t stream) {
  const float* hidden = (const float*)d_in[0];
  const float* Wqkv_w = (const float*)d_in[1];
  const float* Wqkv_b = (const float*)d_in[2];

  constexpr size_t NA_PAD = (size_t)6656 * 768;
  constexpr size_t NW = (size_t)2304 * 768;
  constexpr size_t NP = (size_t)8 * 12 * 1024 * 64;

  short* hb   = (short*)d_ws;
  short* wb   = hb + NA_PAD;
  short* qws  = wb + NW;
  short* kws  = qws + NP;
  short* vtws = kws + NP;

  convert_in<<<dim3(2048), 256, 0, stream>>>(hidden, Wqkv_w, hb, wb);
  qkv_gemm<<<dim3(26, 18), 256, 0, stream>>>(hb, wb, Wqkv_b, qws, kws, vtws);
  attn<<<dim3(12, 51), 256, 0, stream>>>(qws, kws, vtws, (float*)d_out);
}